// Round 4
// baseline (323.871 us; speedup 1.0000x reference)
//
#include <hip/hip_runtime.h>

// LSTM: B=2048, T=512, I=6, H=50, O=3. fp32 in/out, bf16 MFMA inner matmul.
//
// R4: attack the per-step serial chain (R3 showed ~1243 cyc/step wall vs
// ~620 busy; 2-WG TLP does not hide in-phase barrier stalls).
//  - A-vector re-mapped to [x(6)|1|0|h(50)|0pad] so the k=0..7 slice is a
//    STATIC precomputed LDS array Xq[row][t][8] (bf16, built once, 32 KB).
//    The rotating buffer Hbuf holds ONLY h -> no per-step x feed, no wave-3
//    special path, fewer LDS ops to drain at the barrier.
//  - Two INDEPENDENT MFMAs per tile (zero accs, one per K-half) + VALU add:
//    removes one MFMA latency from the chain.
//  - NB=4/WG, grid=512, 2 WGs/CU; 1 barrier/step; manual 2-step unroll makes
//    buffer parity static. Merged activations via wave-private Gs (1 pass:
//    NB=4 gives exactly 64 pairs/wave incl. dummies).
//
// Gate permutation j' = 4*hidx + gate: lane's 4 acc regs = (i,f,g,o) of one
// (batch=col, hidx=4*jt+quad) pair (C-layout col=lane&15, row=quad*4+reg).

#define L2E 1.44269504088896340736f

typedef float  f32x4 __attribute__((ext_vector_type(4)));
typedef short  s16x8 __attribute__((ext_vector_type(8)));   // 8 bf16 bit-patterns

__device__ __forceinline__ float fast_exp2(float x){ return __builtin_amdgcn_exp2f(x); }
__device__ __forceinline__ float fast_rcp (float x){ return __builtin_amdgcn_rcpf(x); }
__device__ __forceinline__ float sigm (float x){ return fast_rcp(1.0f + fast_exp2(-L2E * x)); }
__device__ __forceinline__ float tanhf_(float x){ return 1.0f - 2.0f * fast_rcp(1.0f + fast_exp2((2.0f*L2E) * x)); }

// float -> bf16 bits, round-to-nearest-even
__device__ __forceinline__ unsigned short f2bf(float f){
  unsigned u = __builtin_bit_cast(unsigned, f);
  u = (u + 0x7FFFu + ((u >> 16) & 1u)) >> 16;
  return (unsigned short)u;
}

constexpr int B_ = 2048, T_ = 512, I_ = 6, H_ = 50;
constexpr int NB  = 4;             // batch rows per WG (grid=512 -> 2 WGs/CU)
constexpr int XQP = T_ * 8 + 8;    // Xq row pitch (shorts): 16B/t slices + de-phase pad
constexpr int HP  = 72;            // Hbuf row pitch (shorts): 144 B, de-phases banks
constexpr int NT  = 13;            // j' tiles: 13*16 = 208 >= 200

__global__ __launch_bounds__(256, 2)
void lstm_kernel(const float* __restrict__ x,
                 const float* __restrict__ W_ih, const float* __restrict__ W_hh,
                 const float* __restrict__ b_ih, const float* __restrict__ b_hh,
                 const float* __restrict__ W_out, const float* __restrict__ b_out,
                 float* __restrict__ out)
{
  __shared__ unsigned short Xq[NB][XQP];      // [x_t(6)|1|0] bf16 for all t (static)
  __shared__ unsigned short Hbuf[2][NB][HP];  // h(50) + zero pad, double-buffered
  __shared__ f32x4 Gs[4][64];                 // wave-private merged-gate scratch
  __shared__ float Hlast[NB][H_];

  const int tid  = threadIdx.x;
  const int lane = tid & 63;
  const int wave = tid >> 6;
  const int col  = lane & 15;   // MFMA N index = batch row
  const int quad = lane >> 4;   // MFMA row-group / k-group
  const int b0   = blockIdx.x * NB;

  // merged-lane identity: slot L = col + 4*quad + 16*ti
  const int mb = lane & 3;
  const int mh = 4 * (wave + 4 * (lane >> 4)) + ((lane >> 2) & 3);

  // ---- build Xq: global x (coalesced fp32) -> bf16 slices [x|1|0] ----
  {
    const size_t xbase = (size_t)b0 * (T_ * I_);
    for (int idx = tid; idx < NB * T_ * I_; idx += 256) {
      const int row = idx / (T_ * I_);
      const int rem = idx - row * (T_ * I_);
      const int t = rem / I_, i = rem - t * I_;
      Xq[row][t * 8 + i] = f2bf(x[xbase + idx]);
    }
    for (int s = tid; s < NB * T_; s += 256) {
      const int row = s >> 9, t = s & (T_ - 1);
      Xq[row][t * 8 + 6] = 0x3F80;   // bias column = 1.0
      Xq[row][t * 8 + 7] = 0;
    }
  }
  // ---- zero Hbuf (h0 = 0; pads stay 0 forever) and Gs ----
  for (int i = tid; i < 2 * NB * HP; i += 256) (&Hbuf[0][0][0])[i] = 0;
  {
    float* gz = (float*)&Gs[0][0];
    for (int i = tid; i < 4 * 64 * 4; i += 256) gz[i] = 0.0f;
  }

  // ---- weight fragments (A-operand, once). A-vector k-map:
  // k<6: x -> W_ih[.,k]; k==6: bias; k==7: 0; 8<=k<58: h -> W_hh[.,k-8]; else 0
  s16x8 wfrag[4][2];
  #pragma unroll
  for (int ti = 0; ti < 4; ti++) {
    const int jt = wave + 4 * ti;           // wave-uniform
    if (jt < NT) {
      const int jp = jt * 16 + col;
      #pragma unroll
      for (int kh = 0; kh < 2; kh++) {
        s16x8 w;
        #pragma unroll
        for (int kk = 0; kk < 8; kk++) {
          const int k = kh * 32 + quad * 8 + kk;
          float v = 0.0f;
          if (jp < 200) {
            const int hh = jp >> 2, g = jp & 3;
            const int r = g * 50 + hh;
            if      (k < 6)            v = W_ih[r * 6 + k];
            else if (k == 6)           v = b_ih[r] + b_hh[r];
            else if (k >= 8 && k < 58) v = W_hh[r * 50 + (k - 8)];
          }
          w[kk] = (short)f2bf(v);
        }
        wfrag[ti][kh] = w;
      }
    }
  }

  // ---- per-lane frag pointers (parity-static) ----
  const int row = col & 3;                        // cols 4..15 duplicate rows (broadcast)
  const unsigned short* xqrow = &Xq[row][0];
  const int f0off = row * HP + (quad ? quad * 8 - 8 : 0);   // frag0 h-slice (quad>0)
  const int f1off = row * HP + 24 + quad * 8;               // frag1 h-slice (all quads)
  const unsigned short* hb0 = &Hbuf[0][0][0];
  const unsigned short* hb1 = &Hbuf[1][0][0];

  float c_   = 0.0f;
  float hreg = 0.0f;

  __syncthreads();

  auto STEP = [&](int t, const unsigned short* rd, unsigned short* wr) {
    const s16x8 bfr0 = *(const s16x8*)(quad == 0 ? xqrow + t * 8 : rd + f0off);
    const s16x8 bfr1 = *(const s16x8*)(rd + f1off);

    #pragma unroll
    for (int ti = 0; ti < 4; ti++) {
      const int jt = wave + 4 * ti;
      if (jt < NT) {
        const f32x4 z = {0.f, 0.f, 0.f, 0.f};
        f32x4 p = __builtin_amdgcn_mfma_f32_16x16x32_bf16(wfrag[ti][0], bfr0, z, 0, 0, 0);
        f32x4 q = __builtin_amdgcn_mfma_f32_16x16x32_bf16(wfrag[ti][1], bfr1, z, 0, 0, 0);
        const f32x4 s = p + q;                     // independent MFMAs + add
        if (col < NB) Gs[wave][col + 4 * quad + 16 * ti] = s;   // 2-way banks: free
      }
    }

    // merged read (same-wave LDS: ordered, no barrier); every lane 1 pair
    const f32x4 g = Gs[wave][lane];
    const float gi = sigm (g[0]);
    const float gf = sigm (g[1]);
    const float gg = tanhf_(g[2]);
    const float go = sigm (g[3]);
    c_ = gf * c_ + gi * gg;
    const float hn = go * tanhf_(c_);
    hreg = hn;
    if (mh < H_) wr[mb * HP + mh] = f2bf(hn);

    __syncthreads();   // h writes visible; frag reads of rd complete (lgkm only)
  };

  for (int t = 0; t < T_; t += 2) {
    STEP(t,     hb0, (unsigned short*)hb1);
    STEP(t + 1, hb1, (unsigned short*)hb0);
  }

  // ---- epilogue: logits + softmax ----
  if (mh < H_) Hlast[mb][mh] = hreg;   // fp32 h_last
  __syncthreads();

  if (tid < NB) {
    float l[3];
    #pragma unroll
    for (int o = 0; o < 3; o++) {
      float s = b_out[o];
      for (int k = 0; k < H_; k++) s += W_out[o * H_ + k] * Hlast[tid][k];
      l[o] = s;
    }
    const float m  = fmaxf(l[0], fmaxf(l[1], l[2]));
    const float e0 = fast_exp2((l[0] - m) * L2E);
    const float e1 = fast_exp2((l[1] - m) * L2E);
    const float e2 = fast_exp2((l[2] - m) * L2E);
    const float inv = fast_rcp(e0 + e1 + e2);
    float* op = out + (size_t)(b0 + tid) * 3;
    op[0] = e0 * inv; op[1] = e1 * inv; op[2] = e2 * inv;
  }
}

extern "C" void kernel_launch(void* const* d_in, const int* in_sizes, int n_in,
                              void* d_out, int out_size, void* d_ws, size_t ws_size,
                              hipStream_t stream) {
  const float* x     = (const float*)d_in[0];
  const float* W_ih  = (const float*)d_in[1];
  const float* W_hh  = (const float*)d_in[2];
  const float* b_ih  = (const float*)d_in[3];
  const float* b_hh  = (const float*)d_in[4];
  const float* W_out = (const float*)d_in[5];
  const float* b_out = (const float*)d_in[6];
  lstm_kernel<<<B_ / NB, 256, 0, stream>>>(x, W_ih, W_hh, b_ih, b_hh,
                                           W_out, b_out, (float*)d_out);
}